// Round 3
// baseline (939.310 us; speedup 1.0000x reference)
//
#include <hip/hip_runtime.h>

typedef unsigned short u16;
typedef unsigned int u32;
typedef __attribute__((ext_vector_type(8))) short short8;
typedef __attribute__((ext_vector_type(4))) float floatx4;

#define MFMA16(A,B,C) __builtin_amdgcn_mfma_f32_16x16x32_bf16((A),(B),(C),0,0,0)

// B=4, T=1024, H=16, D=64; rows (b,t,h) = 65536 per side, row index r = (b*1024+t)*16+h
// (identical to the input row order -> featmap reads AND writes are dense).
// out[0] = true softmax map, out[1] = pred map; each B*T*H*T = 67108864 f32.

__device__ __forceinline__ u16 f2bf(float f){
  u32 u = __float_as_uint(f);
  u32 r = (u + 0x7fffu + ((u >> 16) & 1u)) >> 16;
  return (u16)r;
}
__device__ __forceinline__ float bf2f(u16 h){
  return __uint_as_float(((u32)h) << 16);
}
__device__ __forceinline__ short8 ld8(const u16* p){
  return *(const short8*)p;
}

// ---------------- Kernel A: feature map + bf16 hi/lo split ----------------
// Workspace rows in [B][T][H] order = input order: thread gid handles row gid
// (q) or gid-65536 (k). All reads and writes are dense (line-reuse across the
// 16B-per-lane instructions of a wave).
__global__ __launch_bounds__(256) void featmap_kernel(
    const float* __restrict__ q, const float* __restrict__ k,
    const float* __restrict__ Wq, const float* __restrict__ bq,
    const float* __restrict__ Wk, const float* __restrict__ bk,
    u16* __restrict__ qh, u16* __restrict__ ql,
    u16* __restrict__ kh, u16* __restrict__ kl,
    u16* __restrict__ phiq, u16* __restrict__ phik) {
  u32 gid = blockIdx.x * 256u + threadIdx.x;
  bool is_k = gid >= 65536u;
  u32 r = is_k ? (gid - 65536u) : gid;
  const float* __restrict__ x = (is_k ? k : q) + (size_t)r * 64u;
  const float* __restrict__ W = is_k ? Wk : Wq;
  const float* __restrict__ bias = is_k ? bk : bq;

  float xv[64];
#pragma unroll
  for (int i = 0; i < 16; i++) {
    float4 v = ((const float4*)x)[i];
    xv[4 * i + 0] = v.x; xv[4 * i + 1] = v.y;
    xv[4 * i + 2] = v.z; xv[4 * i + 3] = v.w;
  }

  // split store (q gets the 1/sqrt(D)=1/8 scale folded in)
  float scale = is_k ? 1.0f : 0.125f;
  u16* hdst = (is_k ? kh : qh) + (size_t)r * 64u;
  u16* ldst = (is_k ? kl : ql) + (size_t)r * 64u;
#pragma unroll
  for (int c = 0; c < 8; c++) {
    u16 hi[8] __attribute__((aligned(16)));
    u16 lo[8] __attribute__((aligned(16)));
#pragma unroll
    for (int j = 0; j < 8; j++) {
      float xs = xv[c * 8 + j] * scale;
      u16 hb = f2bf(xs);
      hi[j] = hb;
      lo[j] = f2bf(xs - bf2f(hb));
    }
    ((uint4*)hdst)[c] = *(const uint4*)hi;
    ((uint4*)ldst)[c] = *(const uint4*)lo;
  }

  // y = x @ W^T + b ; phi = [exp(y), exp(-y)]
  u16* pdst = (is_k ? phik : phiq) + (size_t)r * 128u;
#pragma unroll
  for (int c = 0; c < 4; c++) {
    float accs[16];
#pragma unroll
    for (int i = 0; i < 16; i++) accs[i] = bias[c * 16 + i];
#pragma unroll
    for (int d = 0; d < 64; d++) {
      float xd = xv[d];
#pragma unroll
      for (int i = 0; i < 16; i++) accs[i] += xd * W[(c * 16 + i) * 64 + d];
    }
    u16 pl[16] __attribute__((aligned(16)));
    u16 pm[16] __attribute__((aligned(16)));
#pragma unroll
    for (int i = 0; i < 16; i++) {
      pl[i] = f2bf(__expf(accs[i]));
      pm[i] = f2bf(__expf(-accs[i]));
    }
    ((uint4*)pdst)[2 * c + 0] = ((const uint4*)pl)[0];
    ((uint4*)pdst)[2 * c + 1] = ((const uint4*)pl)[1];
    ((uint4*)(pdst + 64))[2 * c + 0] = ((const uint4*)pm)[0];
    ((uint4*)(pdst + 64))[2 * c + 1] = ((const uint4*)pm)[1];
  }
}

// ---------------- Kernel B (fused): scores -> LDS -> Z -> coalesced store --
// Transposed MFMA (A=K-side, B=Q-side): lane(quad,n16) reg r holds
// score[q-row = strip*16+n16][k-col = ctg*16+quad*4+r].
// Phase A: 16 waves x 4 ct-tiles -> stage exp(true) and pred into LDS
//          [16 rows][1024 cols] (stride 1028 f32).
// Phase B: wave w owns row w: row-sum both maps (Ztrue, Zpred) via
//          16 vals/lane + shfl tree, then fully-coalesced 1KB stores.
// grid = 64 bh * 64 strips(16 rows), 1024 threads.
__global__ __launch_bounds__(1024) void fused_kernel(
    const u16* __restrict__ qh, const u16* __restrict__ ql,
    const u16* __restrict__ kh, const u16* __restrict__ kl,
    const u16* __restrict__ phiq, const u16* __restrict__ phik,
    float* __restrict__ out) {
  int bh = blockIdx.x >> 6, strip = blockIdx.x & 63;
  int tid = threadIdx.x, w = tid >> 6, lane = tid & 63, quad = lane >> 4, n16 = lane & 15;
  u32 b = (u32)bh >> 4, h = (u32)bh & 15u;

  __shared__ float smT[16][1028];
  __shared__ float smP[16][1028];

  // persistent Q-side fragments (B-operand), q-row t = strip*16 + n16
  u32 tq = (u32)strip * 16u + (u32)n16;
  size_t Rq = (size_t)((b * 1024u + tq) * 16u + h);
  short8 bqh[2], bql[2], bpq[4];
#pragma unroll
  for (int ks = 0; ks < 2; ks++) {
    bqh[ks] = ld8(qh + Rq * 64u + ks * 32 + quad * 8);
    bql[ks] = ld8(ql + Rq * 64u + ks * 32 + quad * 8);
  }
#pragma unroll
  for (int ks = 0; ks < 4; ks++)
    bpq[ks] = ld8(phiq + Rq * 128u + ks * 32 + quad * 8);

  // ---- Phase A: compute tiles, stage into LDS ----
#pragma unroll
  for (int ct = 0; ct < 4; ct++) {
    u32 ctg = (u32)(w * 4 + ct);
    u32 tk = ctg * 16u + (u32)n16;
    size_t Rk = (size_t)((b * 1024u + tk) * 16u + h);
    const u16* kp = kh + Rk * 64u + quad * 8;
    const u16* lp = kl + Rk * 64u + quad * 8;
    const u16* pp = phik + Rk * 128u + quad * 8;
    short8 b0 = ld8(kp), b1 = ld8(kp + 32), c0 = ld8(lp), c1 = ld8(lp + 32);
    short8 p0 = ld8(pp), p1 = ld8(pp + 32), p2 = ld8(pp + 64), p3 = ld8(pp + 96);
    floatx4 acc = {0.f, 0.f, 0.f, 0.f};
    acc = MFMA16(b0, bqh[0], acc);
    acc = MFMA16(b1, bqh[1], acc);
    acc = MFMA16(c0, bqh[0], acc);
    acc = MFMA16(c1, bqh[1], acc);
    acc = MFMA16(b0, bql[0], acc);
    acc = MFMA16(b1, bql[1], acc);
    floatx4 ap = {0.f, 0.f, 0.f, 0.f};
    ap = MFMA16(p0, bpq[0], ap);
    ap = MFMA16(p1, bpq[1], ap);
    ap = MFMA16(p2, bpq[2], ap);
    ap = MFMA16(p3, bpq[3], ap);
    float4 tv;
    tv.x = __expf(acc[0]); tv.y = __expf(acc[1]);
    tv.z = __expf(acc[2]); tv.w = __expf(acc[3]);
    float4 pv;
    pv.x = ap[0]; pv.y = ap[1]; pv.z = ap[2]; pv.w = ap[3];
    *(float4*)&smT[n16][ctg * 16u + quad * 4u] = tv;
    *(float4*)&smP[n16][ctg * 16u + quad * 4u] = pv;
  }
  __syncthreads();

  // ---- Phase B: wave w owns q-row w ----
  float4 tv[4], pv[4];
#pragma unroll
  for (int j = 0; j < 4; j++) {
    tv[j] = *(const float4*)&smT[w][j * 256 + lane * 4];
    pv[j] = *(const float4*)&smP[w][j * 256 + lane * 4];
  }
  float st = 0.f, sp = 0.f;
#pragma unroll
  for (int j = 0; j < 4; j++) {
    st += tv[j].x + tv[j].y + tv[j].z + tv[j].w;
    sp += pv[j].x + pv[j].y + pv[j].z + pv[j].w;
  }
#pragma unroll
  for (int off = 1; off < 64; off <<= 1) {
    st += __shfl_xor(st, off);
    sp += __shfl_xor(sp, off);
  }
  float rzt = 1.f / st, rzp = 1.f / sp;

  u32 tr = (u32)strip * 16u + (u32)w;
  float* out0 = out + (size_t)((b * 1024u + tr) * 16u + h) * 1024u;
  float* out1 = out0 + 67108864u;
#pragma unroll
  for (int j = 0; j < 4; j++) {
    float4 ov;
    ov.x = tv[j].x * rzt; ov.y = tv[j].y * rzt;
    ov.z = tv[j].z * rzt; ov.w = tv[j].w * rzt;
    *(float4*)(out0 + j * 256 + lane * 4) = ov;
    float4 pw;
    pw.x = pv[j].x * rzp; pw.y = pv[j].y * rzp;
    pw.z = pv[j].z * rzp; pw.w = pv[j].w * rzp;
    *(float4*)(out1 + j * 256 + lane * 4) = pw;
  }
}

extern "C" void kernel_launch(void* const* d_in, const int* in_sizes, int n_in,
                              void* d_out, int out_size, void* d_ws, size_t ws_size,
                              hipStream_t stream) {
  const float* q  = (const float*)d_in[0];
  const float* k  = (const float*)d_in[1];
  const float* Wq = (const float*)d_in[2];
  const float* bq = (const float*)d_in[3];
  const float* Wk = (const float*)d_in[4];
  const float* bk = (const float*)d_in[5];
  unsigned char* ws = (unsigned char*)d_ws;
  // ws layout (bytes): qh 8M | ql 8M | kh 8M | kl 8M | phiq 16M | phik 16M
  u16* qh   = (u16*)(ws + (0ull  << 20));
  u16* ql   = (u16*)(ws + (8ull  << 20));
  u16* kh   = (u16*)(ws + (16ull << 20));
  u16* kl   = (u16*)(ws + (24ull << 20));
  u16* phiq = (u16*)(ws + (32ull << 20));
  u16* phik = (u16*)(ws + (48ull << 20));
  float* out = (float*)d_out;

  hipLaunchKernelGGL(featmap_kernel, dim3(512), dim3(256), 0, stream,
                     q, k, Wq, bq, Wk, bk, qh, ql, kh, kl, phiq, phik);
  hipLaunchKernelGGL(fused_kernel, dim3(4096), dim3(1024), 0, stream,
                     qh, ql, kh, kl, phiq, phik, out);
}